// Round 8
// baseline (304.902 us; speedup 1.0000x reference)
//
#include <hip/hip_runtime.h>
#include <hip/hip_bf16.h>
#include <stdint.h>

// Self-attention: out = softmax((xWq+bq)(xWk+bk)^T / 32) (xWv+bv) Wo + bo
// B=4, C=2048, D_IN=D_H=D_OUT=1024. fp32 in/out; bf16 MFMA internally.
// R7 (resubmit of R6): gemm8<HAS_BIAS> 8-phase 256^2 for qkv + scores;
//     pv/out stay 2-phase (256^2 grid would idle half the CUs).

typedef unsigned short u16;
typedef __attribute__((ext_vector_type(8))) short bf16x8;   // 8 bf16 = 4 VGPR
typedef __attribute__((ext_vector_type(8))) unsigned short u16x8;
typedef __attribute__((ext_vector_type(4))) float f32x4;    // MFMA 16x16 acc

#define BATCH 4
#define CSEQ  2048
#define DIM   1024
#define NQKV  3072

__device__ __forceinline__ u16 f2bf(float f) {
  union { float f; uint32_t u; } v; v.f = f;
  uint32_t r = (v.u + 0x7fffu + ((v.u >> 16) & 1u)) >> 16;  // RNE
  return (u16)r;
}
__device__ __forceinline__ float bf2f(u16 h) {
  union { uint32_t u; float f; } v; v.u = (uint32_t)h << 16;
  return v.f;
}

__device__ __forceinline__ void gload_lds16(const void* g, void* lds) {
  // async global->LDS, 16B per lane; LDS dest = wave-uniform base + lane*16
  __builtin_amdgcn_global_load_lds(
      (const __attribute__((address_space(1))) unsigned int*)g,
      (__attribute__((address_space(3))) unsigned int*)lds, 16, 0, 0);
}

// ---------------------------------------------------------------------------
__global__ __launch_bounds__(256) void cast_f32_bf16(
    const float4* __restrict__ in, ushort4* __restrict__ out, int n4) {
  int i = blockIdx.x * 256 + threadIdx.x;
  if (i < n4) {
    float4 v = in[i];
    ushort4 o;
    o.x = f2bf(v.x); o.y = f2bf(v.y); o.z = f2bf(v.z); o.w = f2bf(v.w);
    out[i] = o;
  }
}

// transpose+cast Wq/Wk/Wv (each 1024x1024) into Wt rows [z*1024, z*1024+1024);
// z=0 (Wq) folds the 1/sqrt(D_H)=2^-5 score scale (exact in bf16).
__global__ __launch_bounds__(256) void transpose_cast_qkv(
    const float* __restrict__ Wq, const float* __restrict__ Wk,
    const float* __restrict__ Wv, u16* __restrict__ Wt) {
  const int z = blockIdx.z;
  const float* W = (z == 0) ? Wq : (z == 1) ? Wk : Wv;
  const float sc = (z == 0) ? 0.03125f : 1.0f;
  __shared__ float t[32][33];
  int bx = blockIdx.x * 32, by = blockIdx.y * 32;
  int tx = threadIdx.x, ty = threadIdx.y;  // 32 x 8
#pragma unroll
  for (int i = 0; i < 4; ++i)
    t[ty + i * 8][tx] = W[(size_t)(by + ty + i * 8) * DIM + bx + tx];
  __syncthreads();
#pragma unroll
  for (int i = 0; i < 4; ++i)
    Wt[(size_t)(z * DIM + bx + ty + i * 8) * DIM + by + tx] =
        f2bf(t[tx][ty + i * 8] * sc);
}

__global__ __launch_bounds__(256) void transpose_cast_w(
    const float* __restrict__ W, u16* __restrict__ Wt, int rows, int cols) {
  __shared__ float t[32][33];
  int bx = blockIdx.x * 32, by = blockIdx.y * 32;
  int tx = threadIdx.x, ty = threadIdx.y;
#pragma unroll
  for (int i = 0; i < 4; ++i)
    t[ty + i * 8][tx] = W[(size_t)(by + ty + i * 8) * cols + bx + tx];
  __syncthreads();
#pragma unroll
  for (int i = 0; i < 4; ++i)
    Wt[(size_t)(bx + ty + i * 8) * rows + by + tx] = f2bf(t[tx][ty + i * 8]);
}

// bqkv[3072] = concat(bq * 2^-5, bk, bv)
__global__ __launch_bounds__(256) void concat_bias(
    const float* __restrict__ bq, const float* __restrict__ bk,
    const float* __restrict__ bv, float* __restrict__ bqkv) {
  int i = blockIdx.x * 256 + threadIdx.x;
  if (i < NQKV) {
    float v = (i < 1024) ? bq[i] * 0.03125f
                         : (i < 2048) ? bk[i - 1024] : bv[i - 2048];
    bqkv[i] = v;
  }
}

// generalized bf16 batch transpose: dst[z][c][r] = src[z][r][c]
__global__ __launch_bounds__(256) void transpose_bf16(
    const u16* __restrict__ src, u16* __restrict__ dst, int sld, size_t sbs,
    int dld, size_t dbs) {
  __shared__ u16 t[32][34];
  const size_t sb = (size_t)blockIdx.z * sbs;
  const size_t db = (size_t)blockIdx.z * dbs;
  int bx = blockIdx.x * 32, by = blockIdx.y * 32;
  int tx = threadIdx.x, ty = threadIdx.y;
#pragma unroll
  for (int i = 0; i < 4; ++i)
    t[ty + i * 8][tx] = src[sb + (size_t)(by + ty + i * 8) * sld + bx + tx];
  __syncthreads();
#pragma unroll
  for (int i = 0; i < 4; ++i)
    dst[db + (size_t)(bx + ty + i * 8) * dld + by + tx] = t[tx][ty + i * 8];
}

// ---------------------------------------------------------------------------
// 2-phase 128x128 GEMM (verified R3): C = A[M][K] * Bt[N][K]^T (+bias)(*scale)
template <bool OUT_BF16, bool HAS_BIAS>
__device__ __forceinline__ void gemm_body(
    const u16* __restrict__ A, const u16* __restrict__ Bt, void* __restrict__ C,
    const float* __restrict__ bias, int K, int lda, int ldb, int ldc,
    size_t sA, size_t sB, size_t sC, float scale) {
  __shared__ __align__(16) u16 As[2][128 * 64];
  __shared__ __align__(16) u16 Bs[2][128 * 64];

  const int tid = threadIdx.x;
  const int lane = tid & 63;
  const int w = tid >> 6;
  const int wm = w >> 1, wn = w & 1;
  const int bz = blockIdx.z;
  const int m0 = blockIdx.y * 128;
  const int n0 = blockIdx.x * 128;

  A += (size_t)bz * sA;
  Bt += (size_t)bz * sB;

  f32x4 acc[4][4] = {};

  auto stage = [&](int buf, int k0) {
#pragma unroll
    for (int r = 0; r < 4; ++r) {
      int flat = r * 256 + tid;
      int row = flat >> 3;
      int s = (flat & 7) ^ (row & 7);  // inverse-swizzled source (rule #21)
      const u16* ga = A + (size_t)(m0 + row) * lda + (k0 + s * 8);
      const u16* gb = Bt + (size_t)(n0 + row) * ldb + (k0 + s * 8);
      int ubase = (r * 256 + (tid & ~63)) * 16;
      gload_lds16(ga, (char*)&As[buf][0] + ubase);
      gload_lds16(gb, (char*)&Bs[buf][0] + ubase);
    }
  };

  auto compute = [&](int buf) {
#pragma unroll
    for (int kk = 0; kk < 2; ++kk) {
      bf16x8 a[4], b[4];
#pragma unroll
      for (int i = 0; i < 4; ++i) {
        int rowa = wm * 64 + i * 16 + (lane & 15);
        int sl = kk * 4 + (lane >> 4);
        a[i] = *(const bf16x8*)&As[buf][rowa * 64 + (sl ^ (rowa & 7)) * 8];
        int rowb = wn * 64 + i * 16 + (lane & 15);
        b[i] = *(const bf16x8*)&Bs[buf][rowb * 64 + (sl ^ (rowb & 7)) * 8];
      }
#pragma unroll
      for (int mi = 0; mi < 4; ++mi)
#pragma unroll
        for (int ni = 0; ni < 4; ++ni)
          acc[mi][ni] = __builtin_amdgcn_mfma_f32_16x16x32_bf16(
              a[mi], b[ni], acc[mi][ni], 0, 0, 0);
    }
  };

  const int nk = K >> 6;
  stage(0, 0);
  __syncthreads();
  int buf = 0;
  for (int kt = 0; kt < nk - 1; ++kt) {
    stage(buf ^ 1, (kt + 1) << 6);
    compute(buf);
    __syncthreads();
    buf ^= 1;
  }
  compute(buf);

#pragma unroll
  for (int ni = 0; ni < 4; ++ni) {
    int col = n0 + wn * 64 + ni * 16 + (lane & 15);
    float bv = 0.f;
    if constexpr (HAS_BIAS) bv = bias[col];
#pragma unroll
    for (int mi = 0; mi < 4; ++mi) {
      int row0 = m0 + wm * 64 + mi * 16 + (lane >> 4) * 4;
#pragma unroll
      for (int j = 0; j < 4; ++j) {
        float o = (acc[mi][ni][j] + bv) * scale;
        size_t off = (size_t)bz * sC + (size_t)(row0 + j) * ldc + col;
        if constexpr (OUT_BF16)
          ((u16*)C)[off] = f2bf(o);
        else
          ((float*)C)[off] = o;
      }
    }
  }
}

__global__ __launch_bounds__(256, 2) void gemm_pv(
    const u16* A, const u16* Bt, void* C, const float* bias, int K, int lda,
    int ldb, int ldc, size_t sA, size_t sB, size_t sC, float scale) {
  gemm_body<true, false>(A, Bt, C, bias, K, lda, ldb, ldc, sA, sB, sC, scale);
}
__global__ __launch_bounds__(256, 2) void gemm_out(
    const u16* A, const u16* Bt, void* C, const float* bias, int K, int lda,
    int ldb, int ldc, size_t sA, size_t sB, size_t sC, float scale) {
  gemm_body<false, true>(A, Bt, C, bias, K, lda, ldb, ldc, sA, sB, sC, scale);
}

// ---------------------------------------------------------------------------
// 8-phase 256x256 GEMM (T2+T3+T4+T5), verified R6 as scores kernel.
// 512 thr = 8 waves (2M x 4N), BK=64, per-wave output 128x64, LDS 128 KiB.
// Per K-tile: 4 phases {ds_reads; 1-half stage; bar; lgkm0; 16 MFMA; bar}.
// Counted vmcnt(4) once per tile (T4, never 0 in steady state).
template <bool HAS_BIAS>
__device__ __forceinline__ void gemm8_body(
    const u16* __restrict__ A, const u16* __restrict__ Bt, u16* __restrict__ C,
    const float* __restrict__ bias, int K, int lda, int ldb, int ldc,
    size_t sA, size_t sB, size_t sC) {
  __shared__ __align__(16) u16 As[2][2][128 * 64];
  __shared__ __align__(16) u16 Bs[2][2][128 * 64];

  const int tid = threadIdx.x;   // 0..511
  const int lane = tid & 63;
  const int w = tid >> 6;        // 0..7
  const int wm = w >> 2;         // 0..1  M half
  const int wn = w & 3;          // 0..3  N quarter
  const int bz = blockIdx.z;
  const int m0 = blockIdx.y * 256;
  const int n0 = blockIdx.x * 256;
  A += (size_t)bz * sA;
  Bt += (size_t)bz * sB;

  f32x4 acc[8][4] = {};

  // stage one 16KB half (128 rows x BK=64 bf16): 2 gload_lds per wave
  auto stage_half = [&](u16* ldsHalf, const u16* g, int row0, int ld, int k0) {
#pragma unroll
    for (int r = 0; r < 2; ++r) {
      int flat = r * 512 + tid;        // 16B-unit index 0..1023
      int row = flat >> 3;
      int s = (flat & 7) ^ (row & 7);  // inverse swizzle on source (rule #21)
      const u16* ga = g + (size_t)(row0 + row) * ld + (k0 + s * 8);
      int ubase = (r * 512 + (tid & ~63)) * 16;  // wave-uniform dest
      gload_lds16(ga, (char*)ldsHalf + ubase);
    }
  };

  const int nk = K >> 6;
  // prologue: tile0 fully + tile1's Bh0,Ah0 (order matters for vmcnt count)
  stage_half(As[0][0], A, m0, lda, 0);
  stage_half(As[0][1], A, m0 + 128, lda, 0);
  stage_half(Bs[0][0], Bt, n0, ldb, 0);
  stage_half(Bs[0][1], Bt, n0 + 128, ldb, 0);
  stage_half(Bs[1][0], Bt, n0, ldb, 64);
  stage_half(As[1][0], A, m0, lda, 64);
  asm volatile("s_waitcnt vmcnt(4)" ::: "memory");  // tile0 in; 4 in flight
  asm volatile("s_barrier" ::: "memory");

  for (int t = 0; t < nk; ++t) {
    const int p = t & 1;
    const u16* Abuf = &As[p][wm][0];
    const u16* Bbuf = &Bs[p][wn >> 1][0];
    const int bR0 = (wn & 1) * 64;  // B row base within half
    const int rl = lane & 15;
    const int su = lane >> 4;       // slot sub-index
    bf16x8 a[4][2], b[4][2];

    auto rdA = [&](int fi, int fbase) {
#pragma unroll
      for (int ks = 0; ks < 2; ++ks) {
        int row = (fbase + fi) * 16 + rl;
        int sl = ks * 4 + su;
        a[fi][ks] = *(const bf16x8*)&Abuf[row * 64 + ((sl ^ (row & 7))) * 8];
      }
    };
    auto rdB = [&](int nf) {
#pragma unroll
      for (int ks = 0; ks < 2; ++ks) {
        int row = bR0 + nf * 16 + rl;
        int sl = ks * 4 + su;
        b[nf][ks] = *(const bf16x8*)&Bbuf[row * 64 + ((sl ^ (row & 7))) * 8];
      }
    };
    auto quad = [&](int mbase, int nbase) {
      __builtin_amdgcn_s_setprio(1);
#pragma unroll
      for (int fi = 0; fi < 4; ++fi)
#pragma unroll
        for (int nf = 0; nf < 2; ++nf)
#pragma unroll
          for (int ks = 0; ks < 2; ++ks)
            acc[mbase + fi][nbase + nf] = __builtin_amdgcn_mfma_f32_16x16x32_bf16(
                a[fi][ks], b[nbase + nf][ks], acc[mbase + fi][nbase + nf], 0, 0, 0);
      __builtin_amdgcn_s_setprio(0);
    };
    auto barrier_in = [&]() {
      asm volatile("s_barrier" ::: "memory");
      asm volatile("s_waitcnt lgkmcnt(0)" ::: "memory");
      __builtin_amdgcn_sched_barrier(0);  // rule #18: pin MFMA after the wait
    };

    // ---- phase 0: A0-3, B0-1 -> quad(0,0); stage Bh1(t+1)
    rdA(0, 0); rdA(1, 0); rdA(2, 0); rdA(3, 0);
    rdB(0); rdB(1);
    if (t + 1 < nk) stage_half(Bs[1 - p][1], Bt, n0 + 128, ldb, (t + 1) * 64);
    barrier_in();
    quad(0, 0);
    asm volatile("s_barrier" ::: "memory");

    // ---- phase 1: B2-3 -> quad(0,2); stage Ah1(t+1)
    rdB(2); rdB(3);
    if (t + 1 < nk) stage_half(As[1 - p][1], A, m0 + 128, lda, (t + 1) * 64);
    barrier_in();
    quad(0, 2);
    asm volatile("s_barrier" ::: "memory");

    // ---- phase 2: A4-7 -> quad(4,2); stage Bh0(t+2) into own buffer
    rdA(0, 4); rdA(1, 4); rdA(2, 4); rdA(3, 4);
    if (t + 2 < nk) stage_half(Bs[p][0], Bt, n0, ldb, (t + 2) * 64);
    barrier_in();
    quad(4, 2);
    asm volatile("s_barrier" ::: "memory");

    // ---- phase 3: no reads -> quad(4,0); stage Ah0(t+2); tile-boundary wait
    if (t + 2 < nk) stage_half(As[p][0], A, m0, lda, (t + 2) * 64);
    barrier_in();  // (no lgkm work pending; keeps phase lockstep)
    quad(4, 0);
    if (t + 2 < nk)
      asm volatile("s_waitcnt vmcnt(4)" ::: "memory");  // t+1 landed, 4 fly
    else if (t + 1 < nk)
      asm volatile("s_waitcnt vmcnt(0)" ::: "memory");  // epilogue drain
    asm volatile("s_barrier" ::: "memory");
  }

  const size_t cb = (size_t)bz * sC;
  float bv[4];
#pragma unroll
  for (int nf = 0; nf < 4; ++nf) {
    if constexpr (HAS_BIAS)
      bv[nf] = bias[n0 + wn * 64 + nf * 16 + (lane & 15)];
    else
      bv[nf] = 0.f;
  }
#pragma unroll
  for (int fi = 0; fi < 8; ++fi) {
    int row0 = m0 + wm * 128 + fi * 16 + (lane >> 4) * 4;
#pragma unroll
    for (int nf = 0; nf < 4; ++nf) {
      int col = n0 + wn * 64 + nf * 16 + (lane & 15);
#pragma unroll
      for (int j = 0; j < 4; ++j)
        C[cb + (size_t)(row0 + j) * ldc + col] = f2bf(acc[fi][nf][j] + bv[nf]);
    }
  }
}

__global__ __launch_bounds__(512, 2) void gemm8_qkv(
    const u16* A, const u16* Bt, u16* C, const float* bias, int K, int lda,
    int ldb, int ldc, size_t sA, size_t sB, size_t sC) {
  gemm8_body<true>(A, Bt, C, bias, K, lda, ldb, ldc, sA, sB, sC);
}
__global__ __launch_bounds__(512, 2) void gemm8_scores(
    const u16* A, const u16* Bt, u16* C, const float* bias, int K, int lda,
    int ldb, int ldc, size_t sA, size_t sB, size_t sC) {
  gemm8_body<false>(A, Bt, C, bias, K, lda, ldb, ldc, sA, sB, sC);
}

// ---------------------------------------------------------------------------
// row softmax over bf16 S, fp32 math, in-place (one block per row, 2048 cols)
__global__ __launch_bounds__(256) void softmax_bf16(u16* __restrict__ S) {
  const int t = threadIdx.x;
  const int lane = t & 63;
  const int w = t >> 6;
  u16* base = S + (size_t)blockIdx.x * 2048;
  u16x8 v = *(const u16x8*)(base + t * 8);
  float vals[8];
#pragma unroll
  for (int i = 0; i < 8; ++i) vals[i] = bf2f(v[i]);
  float m = vals[0];
#pragma unroll
  for (int i = 1; i < 8; ++i) m = fmaxf(m, vals[i]);
#pragma unroll
  for (int off = 32; off; off >>= 1) m = fmaxf(m, __shfl_xor(m, off));
  __shared__ float red[8];
  if (lane == 0) red[w] = m;
  __syncthreads();
  m = fmaxf(fmaxf(red[0], red[1]), fmaxf(red[2], red[3]));
  float s = 0.f;
#pragma unroll
  for (int i = 0; i < 8; ++i) {
    vals[i] = __expf(vals[i] - m);
    s += vals[i];
  }
#pragma unroll
  for (int off = 32; off; off >>= 1) s += __shfl_xor(s, off);
  if (lane == 0) red[4 + w] = s;
  __syncthreads();
  s = red[4] + red[5] + red[6] + red[7];
  float inv = 1.0f / s;
  u16x8 o;
#pragma unroll
  for (int i = 0; i < 8; ++i) o[i] = f2bf(vals[i] * inv);
  *(u16x8*)(base + t * 8) = o;
}

// ---------------------------------------------------------------------------
extern "C" void kernel_launch(void* const* d_in, const int* in_sizes, int n_in,
                              void* d_out, int out_size, void* d_ws,
                              size_t ws_size, hipStream_t stream) {
  (void)in_sizes; (void)n_in; (void)out_size; (void)ws_size;
  const float* x  = (const float*)d_in[0];
  const float* Wq = (const float*)d_in[1];
  const float* bq = (const float*)d_in[2];
  const float* Wk = (const float*)d_in[3];
  const float* bk = (const float*)d_in[4];
  const float* Wv = (const float*)d_in[5];
  const float* bv = (const float*)d_in[6];
  const float* Wo = (const float*)d_in[7];
  const float* bo = (const float*)d_in[8];

  const size_t M = (size_t)BATCH * CSEQ;  // 8192
  char* ws = (char*)d_ws;
  size_t off = 0;
  auto alloc = [&](size_t bytes) {
    char* p = ws + off;
    off += (bytes + 255) & ~(size_t)255;
    return p;
  };
  u16* x_bf   = (u16*)alloc(M * DIM * 2);             // 16 MB (attn aliases)
  u16* Wqkv_t = (u16*)alloc((size_t)NQKV * DIM * 2);  // 6 MB
  u16* Wo_t   = (u16*)alloc((size_t)DIM * DIM * 2);   // 2 MB
  float* bqkv = (float*)alloc(NQKV * 4);              // 12 KB
  u16* QKV    = (u16*)alloc(M * NQKV * 2);            // 48 MB
  u16* Vt     = (u16*)alloc(M * DIM * 2);             // 16 MB
  u16* S      = (u16*)alloc((size_t)BATCH * CSEQ * CSEQ * 2);  // 32 MB
  u16* attn   = x_bf;  // x dead after QKV GEMM

  // 1. cast x -> bf16
  int n4 = (int)(M * DIM / 4);
  cast_f32_bf16<<<n4 / 256, 256, 0, stream>>>((const float4*)x,
                                              (ushort4*)x_bf, n4);
  // 2. weights -> bf16 N x K (Q pre-scaled by 2^-5), bias concat
  dim3 tb(32, 8);
  transpose_cast_qkv<<<dim3(32, 32, 3), tb, 0, stream>>>(Wq, Wk, Wv, Wqkv_t);
  transpose_cast_w<<<dim3(32, 32), tb, 0, stream>>>(Wo, Wo_t, DIM, DIM);
  concat_bias<<<(NQKV + 255) / 256, 256, 0, stream>>>(bq, bk, bv, bqkv);

  // 3. fused QKV projection (8-phase): QKV[8192][3072] = x_bf*Wqkv_t^T + bqkv
  gemm8_qkv<<<dim3(NQKV / 256, M / 256, 1), 512, 0, stream>>>(
      x_bf, Wqkv_t, QKV, bqkv, DIM, DIM, DIM, NQKV, 0, 0, 0);

  // 4. V (cols 2048..3071 of QKV) -> Vt[b][h][c]
  transpose_bf16<<<dim3(DIM / 32, CSEQ / 32, BATCH), tb, 0, stream>>>(
      QKV + 2048, Vt, NQKV, (size_t)CSEQ * NQKV, CSEQ, (size_t)DIM * CSEQ);

  // 5. scores S[b] = Qs[b] * K[b]^T  (8-phase; grid = 256 blocks = 1/CU)
  gemm8_scores<<<dim3(CSEQ / 256, CSEQ / 256, BATCH), 512, 0, stream>>>(
      QKV, QKV + 1024, S, nullptr, DIM, NQKV, NQKV, CSEQ,
      (size_t)CSEQ * NQKV, (size_t)CSEQ * NQKV, (size_t)CSEQ * CSEQ);

  // 6. softmax rows, fp32 math, bf16 in-place
  softmax_bf16<<<BATCH * CSEQ, 256, 0, stream>>>(S);

  // 7. attn[b] = P[b] * Vt[b]^T  (2-phase 128^2: full-CU grid)
  gemm_pv<<<dim3(DIM / 128, CSEQ / 128, BATCH), 256, 0, stream>>>(
      S, Vt, attn, nullptr, CSEQ, CSEQ, CSEQ, DIM, (size_t)CSEQ * CSEQ,
      (size_t)DIM * CSEQ, (size_t)CSEQ * DIM, 1.0f);

  // 8. out = attn * Wo_t^T + bo (fp32 out, 2-phase 128^2)
  gemm_out<<<dim3(DIM / 128, M / 128, 1), 256, 0, stream>>>(
      attn, Wo_t, d_out, bo, DIM, DIM, DIM, DIM, 0, 0, 0, 1.0f);
}

// Round 9
// 295.749 us; speedup vs baseline: 1.0309x; 1.0309x over previous
//
#include <hip/hip_runtime.h>
#include <hip/hip_bf16.h>
#include <stdint.h>

// Self-attention: out = softmax((xWq+bq)(xWk+bk)^T / 32) (xWv+bv) Wo + bo
// B=4, C=2048, D_IN=D_H=D_OUT=1024. fp32 in/out; bf16 MFMA internally.
// R8: qkv REVERTED to 2-phase (8-phase 384-block grid = 2 rounds @1blk/CU ->
//     88us > 76us measured; 8-phase only pays when grid%256==0).
//     scores stays 8-phase (256 blocks = 1 round, ~44us).
//     Dispatch count 10->8: bias fused into cast; Wo fused into W-transpose.

typedef unsigned short u16;
typedef __attribute__((ext_vector_type(8))) short bf16x8;   // 8 bf16 = 4 VGPR
typedef __attribute__((ext_vector_type(8))) unsigned short u16x8;
typedef __attribute__((ext_vector_type(4))) float f32x4;    // MFMA 16x16 acc

#define BATCH 4
#define CSEQ  2048
#define DIM   1024
#define NQKV  3072

__device__ __forceinline__ u16 f2bf(float f) {
  union { float f; uint32_t u; } v; v.f = f;
  uint32_t r = (v.u + 0x7fffu + ((v.u >> 16) & 1u)) >> 16;  // RNE
  return (u16)r;
}
__device__ __forceinline__ float bf2f(u16 h) {
  union { uint32_t u; float f; } v; v.u = (uint32_t)h << 16;
  return v.f;
}

__device__ __forceinline__ void gload_lds16(const void* g, void* lds) {
  // async global->LDS, 16B per lane; LDS dest = wave-uniform base + lane*16
  __builtin_amdgcn_global_load_lds(
      (const __attribute__((address_space(1))) unsigned int*)g,
      (__attribute__((address_space(3))) unsigned int*)lds, 16, 0, 0);
}

// ---------------------------------------------------------------------------
// cast x -> bf16; first NQKV threads also build bqkv = concat(bq/32, bk, bv)
__global__ __launch_bounds__(256) void cast_bias(
    const float4* __restrict__ in, ushort4* __restrict__ out, int n4,
    const float* __restrict__ bq, const float* __restrict__ bk,
    const float* __restrict__ bv, float* __restrict__ bqkv) {
  int i = blockIdx.x * 256 + threadIdx.x;
  if (i < n4) {
    float4 v = in[i];
    ushort4 o;
    o.x = f2bf(v.x); o.y = f2bf(v.y); o.z = f2bf(v.z); o.w = f2bf(v.w);
    out[i] = o;
  }
  if (i < NQKV) {
    float v = (i < 1024) ? bq[i] * 0.03125f
                         : (i < 2048) ? bk[i - 1024] : bv[i - 2048];
    bqkv[i] = v;
  }
}

// transpose+cast Wq/Wk/Wv/Wo (z=0..3). z<3 -> Wqkv_t rows [z*1024..); z==0
// folds the 1/sqrt(D_H)=2^-5 score scale (exact in bf16). z==3 -> Wo_t.
__global__ __launch_bounds__(256) void transpose_cast_w4(
    const float* __restrict__ Wq, const float* __restrict__ Wk,
    const float* __restrict__ Wv, const float* __restrict__ Wo,
    u16* __restrict__ Wqkv_t, u16* __restrict__ Wo_t) {
  const int z = blockIdx.z;
  const float* W = (z == 0) ? Wq : (z == 1) ? Wk : (z == 2) ? Wv : Wo;
  u16* dst = (z == 3) ? Wo_t : Wqkv_t + (size_t)z * DIM * DIM;
  const float sc = (z == 0) ? 0.03125f : 1.0f;
  __shared__ float t[32][33];
  int bx = blockIdx.x * 32, by = blockIdx.y * 32;
  int tx = threadIdx.x, ty = threadIdx.y;  // 32 x 8
#pragma unroll
  for (int i = 0; i < 4; ++i)
    t[ty + i * 8][tx] = W[(size_t)(by + ty + i * 8) * DIM + bx + tx];
  __syncthreads();
#pragma unroll
  for (int i = 0; i < 4; ++i)
    dst[(size_t)(bx + ty + i * 8) * DIM + by + tx] =
        f2bf(t[tx][ty + i * 8] * sc);
}

// generalized bf16 batch transpose: dst[z][c][r] = src[z][r][c]
__global__ __launch_bounds__(256) void transpose_bf16(
    const u16* __restrict__ src, u16* __restrict__ dst, int sld, size_t sbs,
    int dld, size_t dbs) {
  __shared__ u16 t[32][34];
  const size_t sb = (size_t)blockIdx.z * sbs;
  const size_t db = (size_t)blockIdx.z * dbs;
  int bx = blockIdx.x * 32, by = blockIdx.y * 32;
  int tx = threadIdx.x, ty = threadIdx.y;
#pragma unroll
  for (int i = 0; i < 4; ++i)
    t[ty + i * 8][tx] = src[sb + (size_t)(by + ty + i * 8) * sld + bx + tx];
  __syncthreads();
#pragma unroll
  for (int i = 0; i < 4; ++i)
    dst[db + (size_t)(bx + ty + i * 8) * dld + by + tx] = t[tx][ty + i * 8];
}

// ---------------------------------------------------------------------------
// 2-phase 128x128 GEMM (verified R3): C = A[M][K] * Bt[N][K]^T (+bias)(*scale)
template <bool OUT_BF16, bool HAS_BIAS>
__device__ __forceinline__ void gemm_body(
    const u16* __restrict__ A, const u16* __restrict__ Bt, void* __restrict__ C,
    const float* __restrict__ bias, int K, int lda, int ldb, int ldc,
    size_t sA, size_t sB, size_t sC, float scale) {
  __shared__ __align__(16) u16 As[2][128 * 64];
  __shared__ __align__(16) u16 Bs[2][128 * 64];

  const int tid = threadIdx.x;
  const int lane = tid & 63;
  const int w = tid >> 6;
  const int wm = w >> 1, wn = w & 1;
  const int bz = blockIdx.z;
  const int m0 = blockIdx.y * 128;
  const int n0 = blockIdx.x * 128;

  A += (size_t)bz * sA;
  Bt += (size_t)bz * sB;

  f32x4 acc[4][4] = {};

  auto stage = [&](int buf, int k0) {
#pragma unroll
    for (int r = 0; r < 4; ++r) {
      int flat = r * 256 + tid;
      int row = flat >> 3;
      int s = (flat & 7) ^ (row & 7);  // inverse-swizzled source (rule #21)
      const u16* ga = A + (size_t)(m0 + row) * lda + (k0 + s * 8);
      const u16* gb = Bt + (size_t)(n0 + row) * ldb + (k0 + s * 8);
      int ubase = (r * 256 + (tid & ~63)) * 16;
      gload_lds16(ga, (char*)&As[buf][0] + ubase);
      gload_lds16(gb, (char*)&Bs[buf][0] + ubase);
    }
  };

  auto compute = [&](int buf) {
#pragma unroll
    for (int kk = 0; kk < 2; ++kk) {
      bf16x8 a[4], b[4];
#pragma unroll
      for (int i = 0; i < 4; ++i) {
        int rowa = wm * 64 + i * 16 + (lane & 15);
        int sl = kk * 4 + (lane >> 4);
        a[i] = *(const bf16x8*)&As[buf][rowa * 64 + (sl ^ (rowa & 7)) * 8];
        int rowb = wn * 64 + i * 16 + (lane & 15);
        b[i] = *(const bf16x8*)&Bs[buf][rowb * 64 + (sl ^ (rowb & 7)) * 8];
      }
#pragma unroll
      for (int mi = 0; mi < 4; ++mi)
#pragma unroll
        for (int ni = 0; ni < 4; ++ni)
          acc[mi][ni] = __builtin_amdgcn_mfma_f32_16x16x32_bf16(
              a[mi], b[ni], acc[mi][ni], 0, 0, 0);
    }
  };

  const int nk = K >> 6;
  stage(0, 0);
  __syncthreads();
  int buf = 0;
  for (int kt = 0; kt < nk - 1; ++kt) {
    stage(buf ^ 1, (kt + 1) << 6);
    compute(buf);
    __syncthreads();
    buf ^= 1;
  }
  compute(buf);

#pragma unroll
  for (int ni = 0; ni < 4; ++ni) {
    int col = n0 + wn * 64 + ni * 16 + (lane & 15);
    float bv = 0.f;
    if constexpr (HAS_BIAS) bv = bias[col];
#pragma unroll
    for (int mi = 0; mi < 4; ++mi) {
      int row0 = m0 + wm * 64 + mi * 16 + (lane >> 4) * 4;
#pragma unroll
      for (int j = 0; j < 4; ++j) {
        float o = (acc[mi][ni][j] + bv) * scale;
        size_t off = (size_t)bz * sC + (size_t)(row0 + j) * ldc + col;
        if constexpr (OUT_BF16)
          ((u16*)C)[off] = f2bf(o);
        else
          ((float*)C)[off] = o;
      }
    }
  }
}

__global__ __launch_bounds__(256, 2) void gemm_qkv(
    const u16* A, const u16* Bt, void* C, const float* bias, int K, int lda,
    int ldb, int ldc, size_t sA, size_t sB, size_t sC, float scale) {
  gemm_body<true, true>(A, Bt, C, bias, K, lda, ldb, ldc, sA, sB, sC, scale);
}
__global__ __launch_bounds__(256, 2) void gemm_pv(
    const u16* A, const u16* Bt, void* C, const float* bias, int K, int lda,
    int ldb, int ldc, size_t sA, size_t sB, size_t sC, float scale) {
  gemm_body<true, false>(A, Bt, C, bias, K, lda, ldb, ldc, sA, sB, sC, scale);
}
__global__ __launch_bounds__(256, 2) void gemm_out(
    const u16* A, const u16* Bt, void* C, const float* bias, int K, int lda,
    int ldb, int ldc, size_t sA, size_t sB, size_t sC, float scale) {
  gemm_body<false, true>(A, Bt, C, bias, K, lda, ldb, ldc, sA, sB, sC, scale);
}

// ---------------------------------------------------------------------------
// 8-phase 256x256 GEMM (T2+T3+T4+T5), verified R6 (scores: 256 blocks=1/CU).
// 512 thr = 8 waves (2M x 4N), BK=64, per-wave output 128x64, LDS 128 KiB.
// Per K-tile: 4 phases {ds_reads; 1-half stage; bar; lgkm0; 16 MFMA; bar}.
// Counted vmcnt(4) once per tile (T4, never 0 in steady state).
__global__ __launch_bounds__(512, 2) void gemm8_scores(
    const u16* __restrict__ A, const u16* __restrict__ Bt, u16* __restrict__ C,
    int K, int lda, int ldb, int ldc, size_t sA, size_t sB, size_t sC) {
  __shared__ __align__(16) u16 As[2][2][128 * 64];
  __shared__ __align__(16) u16 Bs[2][2][128 * 64];

  const int tid = threadIdx.x;   // 0..511
  const int lane = tid & 63;
  const int w = tid >> 6;        // 0..7
  const int wm = w >> 2;         // 0..1  M half
  const int wn = w & 3;          // 0..3  N quarter
  const int bz = blockIdx.z;
  const int m0 = blockIdx.y * 256;
  const int n0 = blockIdx.x * 256;
  A += (size_t)bz * sA;
  Bt += (size_t)bz * sB;

  f32x4 acc[8][4] = {};

  // stage one 16KB half (128 rows x BK=64 bf16): 2 gload_lds per wave
  auto stage_half = [&](u16* ldsHalf, const u16* g, int row0, int ld, int k0) {
#pragma unroll
    for (int r = 0; r < 2; ++r) {
      int flat = r * 512 + tid;        // 16B-unit index 0..1023
      int row = flat >> 3;
      int s = (flat & 7) ^ (row & 7);  // inverse swizzle on source (rule #21)
      const u16* ga = g + (size_t)(row0 + row) * ld + (k0 + s * 8);
      int ubase = (r * 512 + (tid & ~63)) * 16;  // wave-uniform dest
      gload_lds16(ga, (char*)ldsHalf + ubase);
    }
  };

  const int nk = K >> 6;
  // prologue: tile0 fully + tile1's Bh0,Ah0 (order matters for vmcnt count)
  stage_half(As[0][0], A, m0, lda, 0);
  stage_half(As[0][1], A, m0 + 128, lda, 0);
  stage_half(Bs[0][0], Bt, n0, ldb, 0);
  stage_half(Bs[0][1], Bt, n0 + 128, ldb, 0);
  stage_half(Bs[1][0], Bt, n0, ldb, 64);
  stage_half(As[1][0], A, m0, lda, 64);
  asm volatile("s_waitcnt vmcnt(4)" ::: "memory");  // tile0 in; 4 in flight
  asm volatile("s_barrier" ::: "memory");

  for (int t = 0; t < nk; ++t) {
    const int p = t & 1;
    const u16* Abuf = &As[p][wm][0];
    const u16* Bbuf = &Bs[p][wn >> 1][0];
    const int bR0 = (wn & 1) * 64;  // B row base within half
    const int rl = lane & 15;
    const int su = lane >> 4;       // slot sub-index
    bf16x8 a[4][2], b[4][2];

    auto rdA = [&](int fi, int fbase) {
#pragma unroll
      for (int ks = 0; ks < 2; ++ks) {
        int row = (fbase + fi) * 16 + rl;
        int sl = ks * 4 + su;
        a[fi][ks] = *(const bf16x8*)&Abuf[row * 64 + ((sl ^ (row & 7))) * 8];
      }
    };
    auto rdB = [&](int nf) {
#pragma unroll
      for (int ks = 0; ks < 2; ++ks) {
        int row = bR0 + nf * 16 + rl;
        int sl = ks * 4 + su;
        b[nf][ks] = *(const bf16x8*)&Bbuf[row * 64 + ((sl ^ (row & 7))) * 8];
      }
    };
    auto quad = [&](int mbase, int nbase) {
      __builtin_amdgcn_s_setprio(1);
#pragma unroll
      for (int fi = 0; fi < 4; ++fi)
#pragma unroll
        for (int nf = 0; nf < 2; ++nf)
#pragma unroll
          for (int ks = 0; ks < 2; ++ks)
            acc[mbase + fi][nbase + nf] = __builtin_amdgcn_mfma_f32_16x16x32_bf16(
                a[fi][ks], b[nbase + nf][ks], acc[mbase + fi][nbase + nf], 0, 0, 0);
      __builtin_amdgcn_s_setprio(0);
    };
    auto barrier_in = [&]() {
      asm volatile("s_barrier" ::: "memory");
      asm volatile("s_waitcnt lgkmcnt(0)" ::: "memory");
      __builtin_amdgcn_sched_barrier(0);  // rule #18: pin MFMA after the wait
    };

    // ---- phase 0: A0-3, B0-1 -> quad(0,0); stage Bh1(t+1)
    rdA(0, 0); rdA(1, 0); rdA(2, 0); rdA(3, 0);
    rdB(0); rdB(1);
    if (t + 1 < nk) stage_half(Bs[1 - p][1], Bt, n0 + 128, ldb, (t + 1) * 64);
    barrier_in();
    quad(0, 0);
    asm volatile("s_barrier" ::: "memory");

    // ---- phase 1: B2-3 -> quad(0,2); stage Ah1(t+1)
    rdB(2); rdB(3);
    if (t + 1 < nk) stage_half(As[1 - p][1], A, m0 + 128, lda, (t + 1) * 64);
    barrier_in();
    quad(0, 2);
    asm volatile("s_barrier" ::: "memory");

    // ---- phase 2: A4-7 -> quad(4,2); stage Bh0(t+2) into own buffer
    rdA(0, 4); rdA(1, 4); rdA(2, 4); rdA(3, 4);
    if (t + 2 < nk) stage_half(Bs[p][0], Bt, n0, ldb, (t + 2) * 64);
    barrier_in();
    quad(4, 2);
    asm volatile("s_barrier" ::: "memory");

    // ---- phase 3: no reads -> quad(4,0); stage Ah0(t+2); tile-boundary wait
    if (t + 2 < nk) stage_half(As[p][0], A, m0, lda, (t + 2) * 64);
    barrier_in();  // (no lgkm work pending; keeps phase lockstep)
    quad(4, 0);
    if (t + 2 < nk)
      asm volatile("s_waitcnt vmcnt(4)" ::: "memory");  // t+1 landed, 4 fly
    else if (t + 1 < nk)
      asm volatile("s_waitcnt vmcnt(0)" ::: "memory");  // epilogue drain
    asm volatile("s_barrier" ::: "memory");
  }

  const size_t cb = (size_t)bz * sC;
#pragma unroll
  for (int fi = 0; fi < 8; ++fi) {
    int row0 = m0 + wm * 128 + fi * 16 + (lane >> 4) * 4;
#pragma unroll
    for (int nf = 0; nf < 4; ++nf) {
      int col = n0 + wn * 64 + nf * 16 + (lane & 15);
#pragma unroll
      for (int j = 0; j < 4; ++j)
        C[cb + (size_t)(row0 + j) * ldc + col] = f2bf(acc[fi][nf][j]);
    }
  }
}

// ---------------------------------------------------------------------------
// row softmax over bf16 S, fp32 math, in-place (one block per row, 2048 cols)
__global__ __launch_bounds__(256) void softmax_bf16(u16* __restrict__ S) {
  const int t = threadIdx.x;
  const int lane = t & 63;
  const int w = t >> 6;
  u16* base = S + (size_t)blockIdx.x * 2048;
  u16x8 v = *(const u16x8*)(base + t * 8);
  float vals[8];
#pragma unroll
  for (int i = 0; i < 8; ++i) vals[i] = bf2f(v[i]);
  float m = vals[0];
#pragma unroll
  for (int i = 1; i < 8; ++i) m = fmaxf(m, vals[i]);
#pragma unroll
  for (int off = 32; off; off >>= 1) m = fmaxf(m, __shfl_xor(m, off));
  __shared__ float red[8];
  if (lane == 0) red[w] = m;
  __syncthreads();
  m = fmaxf(fmaxf(red[0], red[1]), fmaxf(red[2], red[3]));
  float s = 0.f;
#pragma unroll
  for (int i = 0; i < 8; ++i) {
    vals[i] = __expf(vals[i] - m);
    s += vals[i];
  }
#pragma unroll
  for (int off = 32; off; off >>= 1) s += __shfl_xor(s, off);
  if (lane == 0) red[4 + w] = s;
  __syncthreads();
  s = red[4] + red[5] + red[6] + red[7];
  float inv = 1.0f / s;
  u16x8 o;
#pragma unroll
  for (int i = 0; i < 8; ++i) o[i] = f2bf(vals[i] * inv);
  *(u16x8*)(base + t * 8) = o;
}

// ---------------------------------------------------------------------------
extern "C" void kernel_launch(void* const* d_in, const int* in_sizes, int n_in,
                              void* d_out, int out_size, void* d_ws,
                              size_t ws_size, hipStream_t stream) {
  (void)in_sizes; (void)n_in; (void)out_size; (void)ws_size;
  const float* x  = (const float*)d_in[0];
  const float* Wq = (const float*)d_in[1];
  const float* bq = (const float*)d_in[2];
  const float* Wk = (const float*)d_in[3];
  const float* bk = (const float*)d_in[4];
  const float* Wv = (const float*)d_in[5];
  const float* bv = (const float*)d_in[6];
  const float* Wo = (const float*)d_in[7];
  const float* bo = (const float*)d_in[8];

  const size_t M = (size_t)BATCH * CSEQ;  // 8192
  char* ws = (char*)d_ws;
  size_t off = 0;
  auto alloc = [&](size_t bytes) {
    char* p = ws + off;
    off += (bytes + 255) & ~(size_t)255;
    return p;
  };
  u16* x_bf   = (u16*)alloc(M * DIM * 2);             // 16 MB (attn aliases)
  u16* Wqkv_t = (u16*)alloc((size_t)NQKV * DIM * 2);  // 6 MB
  u16* Wo_t   = (u16*)alloc((size_t)DIM * DIM * 2);   // 2 MB
  float* bqkv = (float*)alloc(NQKV * 4);              // 12 KB
  u16* QKV    = (u16*)alloc(M * NQKV * 2);            // 48 MB
  u16* Vt     = (u16*)alloc(M * DIM * 2);             // 16 MB
  u16* S      = (u16*)alloc((size_t)BATCH * CSEQ * CSEQ * 2);  // 32 MB
  u16* attn   = x_bf;  // x dead after QKV GEMM

  // 1. cast x -> bf16 (+ bias concat fused)
  int n4 = (int)(M * DIM / 4);
  cast_bias<<<n4 / 256, 256, 0, stream>>>((const float4*)x, (ushort4*)x_bf,
                                          n4, bq, bk, bv, bqkv);
  // 2. all four weights -> bf16 N x K (Q pre-scaled by 2^-5)
  dim3 tb(32, 8);
  transpose_cast_w4<<<dim3(32, 32, 4), tb, 0, stream>>>(Wq, Wk, Wv, Wo,
                                                        Wqkv_t, Wo_t);

  // 3. fused QKV projection (2-phase): QKV[8192][3072] = x_bf*Wqkv_t^T + bqkv
  gemm_qkv<<<dim3(NQKV / 128, M / 128, 1), 256, 0, stream>>>(
      x_bf, Wqkv_t, QKV, bqkv, DIM, DIM, DIM, NQKV, 0, 0, 0, 1.0f);

  // 4. V (cols 2048..3071 of QKV) -> Vt[b][h][c]
  transpose_bf16<<<dim3(DIM / 32, CSEQ / 32, BATCH), tb, 0, stream>>>(
      QKV + 2048, Vt, NQKV, (size_t)CSEQ * NQKV, CSEQ, (size_t)DIM * CSEQ);

  // 5. scores S[b] = Qs[b] * K[b]^T  (8-phase; grid = 256 blocks = 1/CU)
  gemm8_scores<<<dim3(CSEQ / 256, CSEQ / 256, BATCH), 512, 0, stream>>>(
      QKV, QKV + 1024, S, DIM, NQKV, NQKV, CSEQ,
      (size_t)CSEQ * NQKV, (size_t)CSEQ * NQKV, (size_t)CSEQ * CSEQ);

  // 6. softmax rows, fp32 math, bf16 in-place
  softmax_bf16<<<BATCH * CSEQ, 256, 0, stream>>>(S);

  // 7. attn[b] = P[b] * Vt[b]^T  (2-phase 128^2: full-CU grid)
  gemm_pv<<<dim3(DIM / 128, CSEQ / 128, BATCH), 256, 0, stream>>>(
      S, Vt, attn, nullptr, CSEQ, CSEQ, CSEQ, DIM, (size_t)CSEQ * CSEQ,
      (size_t)DIM * CSEQ, (size_t)CSEQ * DIM, 1.0f);

  // 8. out = attn * Wo_t^T + bo (fp32 out, 2-phase 128^2)
  gemm_out<<<dim3(DIM / 128, M / 128, 1), 256, 0, stream>>>(
      attn, Wo_t, d_out, bo, DIM, DIM, DIM, DIM, 0, 0, 0, 1.0f);
}

// Round 10
// 288.356 us; speedup vs baseline: 1.0574x; 1.0256x over previous
//
#include <hip/hip_runtime.h>
#include <hip/hip_bf16.h>
#include <stdint.h>

// Self-attention: out = softmax((xWq+bq)(xWk+bk)^T / 32) (xWv+bv) Wo + bo
// B=4, C=2048, D_IN=D_H=D_OUT=1024. fp32 in/out; bf16 MFMA internally.
// R9: dispatch count 8 -> 6 (gap model: ~10us/gap from accounting).
//     prep = cast+bias+all W transposes; softmax_vt = softmax + V-transpose.
//     GEMM bodies unchanged: qkv 2ph (68us), scores 8ph, pv/out 2ph.

typedef unsigned short u16;
typedef __attribute__((ext_vector_type(8))) short bf16x8;   // 8 bf16 = 4 VGPR
typedef __attribute__((ext_vector_type(8))) unsigned short u16x8;
typedef __attribute__((ext_vector_type(4))) float f32x4;    // MFMA 16x16 acc

#define BATCH 4
#define CSEQ  2048
#define DIM   1024
#define NQKV  3072

__device__ __forceinline__ u16 f2bf(float f) {
  union { float f; uint32_t u; } v; v.f = f;
  uint32_t r = (v.u + 0x7fffu + ((v.u >> 16) & 1u)) >> 16;  // RNE
  return (u16)r;
}
__device__ __forceinline__ float bf2f(u16 h) {
  union { uint32_t u; float f; } v; v.u = (uint32_t)h << 16;
  return v.f;
}

__device__ __forceinline__ void gload_lds16(const void* g, void* lds) {
  // async global->LDS, 16B per lane; LDS dest = wave-uniform base + lane*16
  __builtin_amdgcn_global_load_lds(
      (const __attribute__((address_space(1))) unsigned int*)g,
      (__attribute__((address_space(3))) unsigned int*)lds, 16, 0, 0);
}

// ---------------------------------------------------------------------------
// prep: blocks [0,8192): cast x->bf16 (+bqkv concat in first 3072 threads);
//       blocks [8192,12288): transpose+cast Wq/Wk/Wv/Wo (z=0..3; z==0 folds
//       the 1/sqrt(D_H)=2^-5 score scale, exact in bf16).
__global__ __launch_bounds__(256) void prep(
    const float4* __restrict__ x4, ushort4* __restrict__ xbf,
    const float* __restrict__ Wq, const float* __restrict__ Wk,
    const float* __restrict__ Wv, const float* __restrict__ Wo,
    u16* __restrict__ Wqkv_t, u16* __restrict__ Wo_t,
    const float* __restrict__ bq, const float* __restrict__ bk,
    const float* __restrict__ bv, float* __restrict__ bqkv) {
  const int bid = blockIdx.x, tid = threadIdx.x;
  if (bid < 8192) {  // ---- cast + bias
    int i = bid * 256 + tid;  // < 2097152 = n4 exactly
    float4 v = x4[i];
    ushort4 o;
    o.x = f2bf(v.x); o.y = f2bf(v.y); o.z = f2bf(v.z); o.w = f2bf(v.w);
    xbf[i] = o;
    if (i < NQKV) {
      float b = (i < 1024) ? bq[i] * 0.03125f
                           : (i < 2048) ? bk[i - 1024] : bv[i - 2048];
      bqkv[i] = b;
    }
  } else {  // ---- weight transpose (1024 blocks per matrix)
    int b = bid - 8192;
    int z = b >> 10;
    int r = b & 1023;
    int bx = (r & 31) * 32, by = (r >> 5) * 32;
    int tx = tid & 31, ty = tid >> 5;  // 32 x 8
    const float* W = (z == 0) ? Wq : (z == 1) ? Wk : (z == 2) ? Wv : Wo;
    u16* dst = (z == 3) ? Wo_t : Wqkv_t + (size_t)z * DIM * DIM;
    const float sc = (z == 0) ? 0.03125f : 1.0f;
    __shared__ float t[32][33];
#pragma unroll
    for (int i = 0; i < 4; ++i)
      t[ty + i * 8][tx] = W[(size_t)(by + ty + i * 8) * DIM + bx + tx];
    __syncthreads();
#pragma unroll
    for (int i = 0; i < 4; ++i)
      dst[(size_t)(bx + ty + i * 8) * DIM + by + tx] =
          f2bf(t[tx][ty + i * 8] * sc);
  }
}

// ---------------------------------------------------------------------------
// 2-phase 128x128 GEMM (verified R3): C = A[M][K] * Bt[N][K]^T (+bias)(*scale)
template <bool OUT_BF16, bool HAS_BIAS>
__device__ __forceinline__ void gemm_body(
    const u16* __restrict__ A, const u16* __restrict__ Bt, void* __restrict__ C,
    const float* __restrict__ bias, int K, int lda, int ldb, int ldc,
    size_t sA, size_t sB, size_t sC, float scale) {
  __shared__ __align__(16) u16 As[2][128 * 64];
  __shared__ __align__(16) u16 Bs[2][128 * 64];

  const int tid = threadIdx.x;
  const int lane = tid & 63;
  const int w = tid >> 6;
  const int wm = w >> 1, wn = w & 1;
  const int bz = blockIdx.z;
  const int m0 = blockIdx.y * 128;
  const int n0 = blockIdx.x * 128;

  A += (size_t)bz * sA;
  Bt += (size_t)bz * sB;

  f32x4 acc[4][4] = {};

  auto stage = [&](int buf, int k0) {
#pragma unroll
    for (int r = 0; r < 4; ++r) {
      int flat = r * 256 + tid;
      int row = flat >> 3;
      int s = (flat & 7) ^ (row & 7);  // inverse-swizzled source (rule #21)
      const u16* ga = A + (size_t)(m0 + row) * lda + (k0 + s * 8);
      const u16* gb = Bt + (size_t)(n0 + row) * ldb + (k0 + s * 8);
      int ubase = (r * 256 + (tid & ~63)) * 16;
      gload_lds16(ga, (char*)&As[buf][0] + ubase);
      gload_lds16(gb, (char*)&Bs[buf][0] + ubase);
    }
  };

  auto compute = [&](int buf) {
#pragma unroll
    for (int kk = 0; kk < 2; ++kk) {
      bf16x8 a[4], b[4];
#pragma unroll
      for (int i = 0; i < 4; ++i) {
        int rowa = wm * 64 + i * 16 + (lane & 15);
        int sl = kk * 4 + (lane >> 4);
        a[i] = *(const bf16x8*)&As[buf][rowa * 64 + (sl ^ (rowa & 7)) * 8];
        int rowb = wn * 64 + i * 16 + (lane & 15);
        b[i] = *(const bf16x8*)&Bs[buf][rowb * 64 + (sl ^ (rowb & 7)) * 8];
      }
#pragma unroll
      for (int mi = 0; mi < 4; ++mi)
#pragma unroll
        for (int ni = 0; ni < 4; ++ni)
          acc[mi][ni] = __builtin_amdgcn_mfma_f32_16x16x32_bf16(
              a[mi], b[ni], acc[mi][ni], 0, 0, 0);
    }
  };

  const int nk = K >> 6;
  stage(0, 0);
  __syncthreads();
  int buf = 0;
  for (int kt = 0; kt < nk - 1; ++kt) {
    stage(buf ^ 1, (kt + 1) << 6);
    compute(buf);
    __syncthreads();
    buf ^= 1;
  }
  compute(buf);

#pragma unroll
  for (int ni = 0; ni < 4; ++ni) {
    int col = n0 + wn * 64 + ni * 16 + (lane & 15);
    float bv = 0.f;
    if constexpr (HAS_BIAS) bv = bias[col];
#pragma unroll
    for (int mi = 0; mi < 4; ++mi) {
      int row0 = m0 + wm * 64 + mi * 16 + (lane >> 4) * 4;
#pragma unroll
      for (int j = 0; j < 4; ++j) {
        float o = (acc[mi][ni][j] + bv) * scale;
        size_t off = (size_t)bz * sC + (size_t)(row0 + j) * ldc + col;
        if constexpr (OUT_BF16)
          ((u16*)C)[off] = f2bf(o);
        else
          ((float*)C)[off] = o;
      }
    }
  }
}

__global__ __launch_bounds__(256, 2) void gemm_qkv(
    const u16* A, const u16* Bt, void* C, const float* bias, int K, int lda,
    int ldb, int ldc, size_t sA, size_t sB, size_t sC, float scale) {
  gemm_body<true, true>(A, Bt, C, bias, K, lda, ldb, ldc, sA, sB, sC, scale);
}
__global__ __launch_bounds__(256, 2) void gemm_pv(
    const u16* A, const u16* Bt, void* C, const float* bias, int K, int lda,
    int ldb, int ldc, size_t sA, size_t sB, size_t sC, float scale) {
  gemm_body<true, false>(A, Bt, C, bias, K, lda, ldb, ldc, sA, sB, sC, scale);
}
__global__ __launch_bounds__(256, 2) void gemm_out(
    const u16* A, const u16* Bt, void* C, const float* bias, int K, int lda,
    int ldb, int ldc, size_t sA, size_t sB, size_t sC, float scale) {
  gemm_body<false, true>(A, Bt, C, bias, K, lda, ldb, ldc, sA, sB, sC, scale);
}

// ---------------------------------------------------------------------------
// 8-phase 256x256 GEMM (T2+T3+T4+T5), verified R6 (scores: 256 blocks=1/CU).
// 512 thr = 8 waves (2M x 4N), BK=64, per-wave output 128x64, LDS 128 KiB.
// Per K-tile: 4 phases {ds_reads; 1-half stage; bar; lgkm0; 16 MFMA; bar}.
// Counted vmcnt(4) once per tile (T4, never 0 in steady state).
__global__ __launch_bounds__(512, 2) void gemm8_scores(
    const u16* __restrict__ A, const u16* __restrict__ Bt, u16* __restrict__ C,
    int K, int lda, int ldb, int ldc, size_t sA, size_t sB, size_t sC) {
  __shared__ __align__(16) u16 As[2][2][128 * 64];
  __shared__ __align__(16) u16 Bs[2][2][128 * 64];

  const int tid = threadIdx.x;   // 0..511
  const int lane = tid & 63;
  const int w = tid >> 6;        // 0..7
  const int wm = w >> 2;         // 0..1  M half
  const int wn = w & 3;          // 0..3  N quarter
  const int bz = blockIdx.z;
  const int m0 = blockIdx.y * 256;
  const int n0 = blockIdx.x * 256;
  A += (size_t)bz * sA;
  Bt += (size_t)bz * sB;

  f32x4 acc[8][4] = {};

  // stage one 16KB half (128 rows x BK=64 bf16): 2 gload_lds per wave
  auto stage_half = [&](u16* ldsHalf, const u16* g, int row0, int ld, int k0) {
#pragma unroll
    for (int r = 0; r < 2; ++r) {
      int flat = r * 512 + tid;        // 16B-unit index 0..1023
      int row = flat >> 3;
      int s = (flat & 7) ^ (row & 7);  // inverse swizzle on source (rule #21)
      const u16* ga = g + (size_t)(row0 + row) * ld + (k0 + s * 8);
      int ubase = (r * 512 + (tid & ~63)) * 16;  // wave-uniform dest
      gload_lds16(ga, (char*)ldsHalf + ubase);
    }
  };

  const int nk = K >> 6;
  // prologue: tile0 fully + tile1's Bh0,Ah0 (order matters for vmcnt count)
  stage_half(As[0][0], A, m0, lda, 0);
  stage_half(As[0][1], A, m0 + 128, lda, 0);
  stage_half(Bs[0][0], Bt, n0, ldb, 0);
  stage_half(Bs[0][1], Bt, n0 + 128, ldb, 0);
  stage_half(Bs[1][0], Bt, n0, ldb, 64);
  stage_half(As[1][0], A, m0, lda, 64);
  asm volatile("s_waitcnt vmcnt(4)" ::: "memory");  // tile0 in; 4 in flight
  asm volatile("s_barrier" ::: "memory");

  for (int t = 0; t < nk; ++t) {
    const int p = t & 1;
    const u16* Abuf = &As[p][wm][0];
    const u16* Bbuf = &Bs[p][wn >> 1][0];
    const int bR0 = (wn & 1) * 64;  // B row base within half
    const int rl = lane & 15;
    const int su = lane >> 4;       // slot sub-index
    bf16x8 a[4][2], b[4][2];

    auto rdA = [&](int fi, int fbase) {
#pragma unroll
      for (int ks = 0; ks < 2; ++ks) {
        int row = (fbase + fi) * 16 + rl;
        int sl = ks * 4 + su;
        a[fi][ks] = *(const bf16x8*)&Abuf[row * 64 + ((sl ^ (row & 7))) * 8];
      }
    };
    auto rdB = [&](int nf) {
#pragma unroll
      for (int ks = 0; ks < 2; ++ks) {
        int row = bR0 + nf * 16 + rl;
        int sl = ks * 4 + su;
        b[nf][ks] = *(const bf16x8*)&Bbuf[row * 64 + ((sl ^ (row & 7))) * 8];
      }
    };
    auto quad = [&](int mbase, int nbase) {
      __builtin_amdgcn_s_setprio(1);
#pragma unroll
      for (int fi = 0; fi < 4; ++fi)
#pragma unroll
        for (int nf = 0; nf < 2; ++nf)
#pragma unroll
          for (int ks = 0; ks < 2; ++ks)
            acc[mbase + fi][nbase + nf] = __builtin_amdgcn_mfma_f32_16x16x32_bf16(
                a[fi][ks], b[nbase + nf][ks], acc[mbase + fi][nbase + nf], 0, 0, 0);
      __builtin_amdgcn_s_setprio(0);
    };
    auto barrier_in = [&]() {
      asm volatile("s_barrier" ::: "memory");
      asm volatile("s_waitcnt lgkmcnt(0)" ::: "memory");
      __builtin_amdgcn_sched_barrier(0);  // rule #18: pin MFMA after the wait
    };

    // ---- phase 0: A0-3, B0-1 -> quad(0,0); stage Bh1(t+1)
    rdA(0, 0); rdA(1, 0); rdA(2, 0); rdA(3, 0);
    rdB(0); rdB(1);
    if (t + 1 < nk) stage_half(Bs[1 - p][1], Bt, n0 + 128, ldb, (t + 1) * 64);
    barrier_in();
    quad(0, 0);
    asm volatile("s_barrier" ::: "memory");

    // ---- phase 1: B2-3 -> quad(0,2); stage Ah1(t+1)
    rdB(2); rdB(3);
    if (t + 1 < nk) stage_half(As[1 - p][1], A, m0 + 128, lda, (t + 1) * 64);
    barrier_in();
    quad(0, 2);
    asm volatile("s_barrier" ::: "memory");

    // ---- phase 2: A4-7 -> quad(4,2); stage Bh0(t+2) into own buffer
    rdA(0, 4); rdA(1, 4); rdA(2, 4); rdA(3, 4);
    if (t + 2 < nk) stage_half(Bs[p][0], Bt, n0, ldb, (t + 2) * 64);
    barrier_in();
    quad(4, 2);
    asm volatile("s_barrier" ::: "memory");

    // ---- phase 3: no reads -> quad(4,0); stage Ah0(t+2); tile-boundary wait
    if (t + 2 < nk) stage_half(As[p][0], A, m0, lda, (t + 2) * 64);
    barrier_in();  // (no lgkm work pending; keeps phase lockstep)
    quad(4, 0);
    if (t + 2 < nk)
      asm volatile("s_waitcnt vmcnt(4)" ::: "memory");  // t+1 landed, 4 fly
    else if (t + 1 < nk)
      asm volatile("s_waitcnt vmcnt(0)" ::: "memory");  // epilogue drain
    asm volatile("s_barrier" ::: "memory");
  }

  const size_t cb = (size_t)bz * sC;
#pragma unroll
  for (int fi = 0; fi < 8; ++fi) {
    int row0 = m0 + wm * 128 + fi * 16 + (lane >> 4) * 4;
#pragma unroll
    for (int nf = 0; nf < 4; ++nf) {
      int col = n0 + wn * 64 + nf * 16 + (lane & 15);
#pragma unroll
      for (int j = 0; j < 4; ++j)
        C[cb + (size_t)(row0 + j) * ldc + col] = f2bf(acc[fi][nf][j]);
    }
  }
}

// ---------------------------------------------------------------------------
// softmax_vt: blocks [0,8192): row softmax over bf16 S, fp32 math, in-place;
//             blocks [8192,16384): transpose V (cols 2048..3071 of QKV) -> Vt.
__global__ __launch_bounds__(256) void softmax_vt(
    u16* __restrict__ S, const u16* __restrict__ QKV, u16* __restrict__ Vt) {
  __shared__ __align__(16) u16 t[32][34];  // vtrans tile; aliased as red[]
  const int tid = threadIdx.x;
  if (blockIdx.x < 8192) {  // ---- softmax
    float* red = (float*)&t[0][0];
    const int lane = tid & 63;
    const int w = tid >> 6;
    u16* base = S + (size_t)blockIdx.x * 2048;
    u16x8 v = *(const u16x8*)(base + tid * 8);
    float vals[8];
#pragma unroll
    for (int i = 0; i < 8; ++i) vals[i] = bf2f(v[i]);
    float m = vals[0];
#pragma unroll
    for (int i = 1; i < 8; ++i) m = fmaxf(m, vals[i]);
#pragma unroll
    for (int off = 32; off; off >>= 1) m = fmaxf(m, __shfl_xor(m, off));
    if (lane == 0) red[w] = m;
    __syncthreads();
    m = fmaxf(fmaxf(red[0], red[1]), fmaxf(red[2], red[3]));
    float s = 0.f;
#pragma unroll
    for (int i = 0; i < 8; ++i) {
      vals[i] = __expf(vals[i] - m);
      s += vals[i];
    }
#pragma unroll
    for (int off = 32; off; off >>= 1) s += __shfl_xor(s, off);
    if (lane == 0) red[4 + w] = s;
    __syncthreads();
    s = red[4] + red[5] + red[6] + red[7];
    float inv = 1.0f / s;
    u16x8 o;
#pragma unroll
    for (int i = 0; i < 8; ++i) o[i] = f2bf(vals[i] * inv);
    *(u16x8*)(base + tid * 8) = o;
  } else {  // ---- V transpose (2048 blocks per batch)
    int b = blockIdx.x - 8192;
    int z = b >> 11;
    int r = b & 2047;
    int bx = (r & 31) * 32;   // h-tile base (DIM/32 = 32 tiles)
    int by = (r >> 5) * 32;   // c-tile base (CSEQ/32 = 64 tiles)
    int tx = tid & 31, ty = tid >> 5;
    const u16* src = QKV + 2048 + (size_t)z * CSEQ * NQKV;
    u16* dst = Vt + (size_t)z * DIM * CSEQ;
#pragma unroll
    for (int i = 0; i < 4; ++i)
      t[ty + i * 8][tx] = src[(size_t)(by + ty + i * 8) * NQKV + bx + tx];
    __syncthreads();
#pragma unroll
    for (int i = 0; i < 4; ++i)
      dst[(size_t)(bx + ty + i * 8) * CSEQ + by + tx] = t[tx][ty + i * 8];
  }
}

// ---------------------------------------------------------------------------
extern "C" void kernel_launch(void* const* d_in, const int* in_sizes, int n_in,
                              void* d_out, int out_size, void* d_ws,
                              size_t ws_size, hipStream_t stream) {
  (void)in_sizes; (void)n_in; (void)out_size; (void)ws_size;
  const float* x  = (const float*)d_in[0];
  const float* Wq = (const float*)d_in[1];
  const float* bq = (const float*)d_in[2];
  const float* Wk = (const float*)d_in[3];
  const float* bk = (const float*)d_in[4];
  const float* Wv = (const float*)d_in[5];
  const float* bv = (const float*)d_in[6];
  const float* Wo = (const float*)d_in[7];
  const float* bo = (const float*)d_in[8];

  const size_t M = (size_t)BATCH * CSEQ;  // 8192
  char* ws = (char*)d_ws;
  size_t off = 0;
  auto alloc = [&](size_t bytes) {
    char* p = ws + off;
    off += (bytes + 255) & ~(size_t)255;
    return p;
  };
  u16* x_bf   = (u16*)alloc(M * DIM * 2);             // 16 MB (attn aliases)
  u16* Wqkv_t = (u16*)alloc((size_t)NQKV * DIM * 2);  // 6 MB
  u16* Wo_t   = (u16*)alloc((size_t)DIM * DIM * 2);   // 2 MB
  float* bqkv = (float*)alloc(NQKV * 4);              // 12 KB
  u16* QKV    = (u16*)alloc(M * NQKV * 2);            // 48 MB
  u16* Vt     = (u16*)alloc(M * DIM * 2);             // 16 MB
  u16* S      = (u16*)alloc((size_t)BATCH * CSEQ * CSEQ * 2);  // 32 MB
  u16* attn   = x_bf;  // x dead after QKV GEMM

  // 1. prep: cast x->bf16 + bias concat + all 4 weight transposes
  prep<<<8192 + 4096, 256, 0, stream>>>((const float4*)x, (ushort4*)x_bf,
                                        Wq, Wk, Wv, Wo, Wqkv_t, Wo_t,
                                        bq, bk, bv, bqkv);

  // 2. fused QKV projection (2-phase): QKV[8192][3072] = x_bf*Wqkv_t^T + bqkv
  gemm_qkv<<<dim3(NQKV / 128, M / 128, 1), 256, 0, stream>>>(
      x_bf, Wqkv_t, QKV, bqkv, DIM, DIM, DIM, NQKV, 0, 0, 0, 1.0f);

  // 3. scores S[b] = Qs[b] * K[b]^T  (8-phase; grid = 256 blocks = 1/CU)
  gemm8_scores<<<dim3(CSEQ / 256, CSEQ / 256, BATCH), 512, 0, stream>>>(
      QKV, QKV + 1024, S, DIM, NQKV, NQKV, CSEQ,
      (size_t)CSEQ * NQKV, (size_t)CSEQ * NQKV, (size_t)CSEQ * CSEQ);

  // 4. softmax rows (in-place) + V transpose out of QKV
  softmax_vt<<<8192 + 8192, 256, 0, stream>>>(S, QKV, Vt);

  // 5. attn[b] = P[b] * Vt[b]^T  (2-phase 128^2: full-CU grid)
  gemm_pv<<<dim3(DIM / 128, CSEQ / 128, BATCH), 256, 0, stream>>>(
      S, Vt, attn, nullptr, CSEQ, CSEQ, CSEQ, DIM, (size_t)CSEQ * CSEQ,
      (size_t)DIM * CSEQ, (size_t)CSEQ * DIM, 1.0f);

  // 6. out = attn * Wo_t^T + bo (fp32 out, 2-phase 128^2)
  gemm_out<<<dim3(DIM / 128, M / 128, 1), 256, 0, stream>>>(
      attn, Wo_t, d_out, bo, DIM, DIM, DIM, DIM, 0, 0, 0, 1.0f);
}